// Round 5
// baseline (662.465 us; speedup 1.0000x reference)
//
#include <hip/hip_runtime.h>
#include <hip/hip_bf16.h>

// GCN 2-layer: h1 = relu(GCNConv(x, W1, b1)); out = log_softmax(GCNConv(h1, W2, b2))
// GCNConv(h)[d] = dinv[d] * ( sum_{s->d} (h@W)[s]*dinv[s] + (h@W)[d]*dinv[d] ) + b
//
// Round-15: kill the CSR. r4 proved direct global-atomic CSR fill is a
// latency disaster (120us, WRITE amplification 16x); r0-r3 bracketing shows
// baseline splits ~evenly between bucket pipeline and gather phase, with the
// col build (scattered 4B writes) + col re-reads (2x6.4MB) as pure overhead.
// part[] (bucket-ordered COO, 8-bit local dst) is already an adjacency
// structure: aggregate edge-parallel per bucket into LDS f32 acc via
// ds_add_f32 (non-returning, ~800K wave DS-instrs total; [256][33] padding
// keeps every phase <=2-way bank conflicts = free). Deletes bucket_csr scan +
// col fill, col reads, row_start, per-node loop tails. Keeps coalesced
// self-terms, coalesced h2/out writes, contiguous part streaming.

#define FEAT_IN 64
#define FEAT_H  32
#define FEAT_O  16
#define MAXNB   512   // max buckets of 256 nodes (n <= 131072; n < 2^24 for packing)
#define PART_G  256   // histogram/partition blocks
#define MAXSNB  128   // max scan blocks for hlen = MAXNB*PART_G

__device__ __forceinline__ float2 upk_bf2(unsigned w) {
    return make_float2(__uint_as_float(w << 16), __uint_as_float(w & 0xFFFF0000u));
}

// ---- pass 1: per-block bucket histogram -> hist[b*G + g] ----
__global__ void k_hist(const int* __restrict__ dst, int e,
                       int* __restrict__ hist, int G, int NBk) {
    __shared__ int lh[MAXNB];
    int t = threadIdx.x, g = blockIdx.x;
    for (int i = t; i < NBk; i += 256) lh[i] = 0;
    __syncthreads();
    int chunk = (e + G - 1) / G;
    int beg = g * chunk, end = min(e, beg + chunk);
    for (int i = beg + t; i < end; i += 256) atomicAdd(&lh[dst[i] >> 8], 1);
    __syncthreads();
    for (int i = t; i < NBk; i += 256) hist[(size_t)i * G + g] = lh[i];
}

// ---- block-local exclusive scan (1024 items/block); bsum[b] = raw block sum ----
__global__ void k_scan1(const int* __restrict__ in, int* __restrict__ out,
                        int* __restrict__ bsum, int len) {
    __shared__ int s[256];
    int t = threadIdx.x;
    int base = blockIdx.x * 1024 + t * 4;
    int a0 = (base + 0) < len ? in[base + 0] : 0;
    int a1 = (base + 1) < len ? in[base + 1] : 0;
    int a2 = (base + 2) < len ? in[base + 2] : 0;
    int a3 = (base + 3) < len ? in[base + 3] : 0;
    int tsum = a0 + a1 + a2 + a3;
    s[t] = tsum;
    __syncthreads();
    for (int off = 1; off < 256; off <<= 1) {
        int x = (t >= off) ? s[t - off] : 0;
        __syncthreads();
        s[t] += x;
        __syncthreads();
    }
    int ex = s[t] - tsum;
    if (base + 0 < len) out[base + 0] = ex;
    if (base + 1 < len) out[base + 1] = ex + a0;
    if (base + 2 < len) out[base + 2] = ex + a0 + a1;
    if (base + 3 < len) out[base + 3] = ex + a0 + a1 + a2;
    if (t == 255) bsum[blockIdx.x] = s[255];
}

// helper: LDS-exclusive-scan of raw bsum[snb] into sps[]
__device__ __forceinline__ void scan_bsum(const int* __restrict__ bsum, int snb,
                                          int* __restrict__ sps, int t) {
    if (t < snb) sps[t] = bsum[t];
    __syncthreads();
    if (t == 0) {
        int acc = 0;
        for (int i = 0; i < snb; ++i) { int v = sps[i]; sps[i] = acc; acc += v; }
    }
    __syncthreads();
}

// ---- bucket edge ranges: bucket_start[i] = base[i*G] + scanned_bsum ----
__global__ void k_fixb(const int* __restrict__ base, const int* __restrict__ bsum,
                       int snb, int G, int NBk, int e, int* __restrict__ bucket_start) {
    __shared__ int sps[MAXSNB];
    int t = threadIdx.x;
    scan_bsum(bsum, snb, sps, t);
    for (int i = t; i <= NBk; i += 256)
        bucket_start[i] = (i == NBk) ? e : (base[(size_t)i * G] + sps[(i * G) >> 10]);
}

// ---- pass 2: scatter packed (src | dlow<<24) into bucket-ordered part[] ----
__global__ void k_partition(const int* __restrict__ src, const int* __restrict__ dst, int e,
                            const int* __restrict__ base, const int* __restrict__ bsum,
                            int snb, int* __restrict__ part, int G, int NBk) {
    __shared__ int cur[MAXNB];
    __shared__ int sps[MAXSNB];
    int t = threadIdx.x, g = blockIdx.x;
    scan_bsum(bsum, snb, sps, t);
    for (int i = t; i < NBk; i += 256) {
        size_t idx = (size_t)i * G + g;
        cur[i] = base[idx] + sps[idx >> 10];
    }
    __syncthreads();
    int chunk = (e + G - 1) / G;
    int beg = g * chunk, end = min(e, beg + chunk);
    for (int i = beg + t; i < end; i += 256) {
        int s_ = src[i], d_ = dst[i];
        int pos = atomicAdd(&cur[d_ >> 8], 1);
        part[pos] = s_ | ((d_ & 255) << 24);   // n < 2^24
    }
}

// ---- per-node degree -> dinv (one bucket per block, contiguous part range) ----
__global__ void k_bdeg(const int* __restrict__ part, const int* __restrict__ bucket_start,
                       int n, float* __restrict__ dinv) {
    __shared__ int cnt[256];
    int t = threadIdx.x, b = blockIdx.x;
    cnt[t] = 0;
    int bs = bucket_start[b], be = bucket_start[b + 1];
    __syncthreads();
    for (int j = bs + t; j < be; j += 256) atomicAdd(&cnt[((unsigned)part[j]) >> 24], 1);
    __syncthreads();
    int d = b * 256 + t;
    if (d < n) dinv[d] = rsqrtf((float)cnt[t] + 1.0f);  // +1 self-loop
}

// ---- layer 1 GEMM: h1s(bf16) = (x @ W1) * dinv ; 32 nodes/block ----
__global__ void k_gemm1(const float* __restrict__ x, const float* __restrict__ W1,
                        const float* __restrict__ dinv,
                        __hip_bfloat162* __restrict__ h1s2, int n) {
    __shared__ float sW[FEAT_IN * FEAT_H];   // 8 KB
    __shared__ float sx[16][FEAT_IN + 1];
    int t = threadIdx.x;
    for (int i = t; i < FEAT_IN * FEAT_H; i += 256) sW[i] = W1[i];
#pragma unroll
    for (int tile = 0; tile < 2; ++tile) {
        int nodeBase = blockIdx.x * 32 + tile * 16;
        __syncthreads();
        {   // stage 16 nodes of x
            int xn = t >> 4, c = t & 15;
            int node = nodeBase + xn;
            if (node < n) {
                float4 v = ((const float4*)x)[(size_t)node * 16 + c];
                sx[xn][c * 4 + 0] = v.x; sx[xn][c * 4 + 1] = v.y;
                sx[xn][c * 4 + 2] = v.z; sx[xn][c * 4 + 3] = v.w;
            }
        }
        __syncthreads();
        int nl = t >> 4, g = t & 15;
        int node = nodeBase + nl;
        if (node < n) {
            float a0 = 0.0f, a1 = 0.0f;
#pragma unroll
            for (int k = 0; k < FEAT_IN; ++k) {
                float s = sx[nl][k];
                a0 += s * sW[k * FEAT_H + 2 * g];
                a1 += s * sW[k * FEAT_H + 2 * g + 1];
            }
            float dv = dinv[node];
            __hip_bfloat162 o;
            o.x = __float2bfloat16(a0 * dv);
            o.y = __float2bfloat16(a1 * dv);
            h1s2[(size_t)node * 16 + g] = o;
        }
    }
}

// ---- layer-1 aggregate (edge-parallel, LDS acc) + relu + bias + GEMM2 ----
// one bucket (256 dst nodes) per block; 1024 threads
__global__ void __launch_bounds__(1024)
k_agg1(const int* __restrict__ part, const int* __restrict__ bucket_start,
       const uint4* __restrict__ h1q, const unsigned short* __restrict__ h1u,
       const float* __restrict__ W2, const float* __restrict__ b1,
       const float* __restrict__ dinv, __hip_bfloat162* __restrict__ h2s2, int n) {
    __shared__ float acc[256 * 33];          // padded: all phases <=2-way conflicts
    __shared__ float sW[FEAT_H * FEAT_O];
    __shared__ float sb1[FEAT_H];
    int t = threadIdx.x, b = blockIdx.x;
    for (int i = t; i < FEAT_H * FEAT_O; i += 1024) sW[i] = W2[i];
    if (t < FEAT_H) sb1[t] = b1[t];
    for (int i = t; i < 256 * 33; i += 1024) acc[i] = 0.0f;
    int bs = bucket_start[b], be = bucket_start[b + 1];
    __syncthreads();
    // edge phase: 32 lanes per edge, one feat each; 32 edges per block round
    int grp = t >> 5, q = t & 31;
    for (int j = bs + grp; j < be; j += 32) {
        int r = part[j];
        int s = r & 0x00FFFFFF;
        int dl = ((unsigned)r) >> 24;
        float v = __uint_as_float((unsigned)h1u[(size_t)s * 32 + q] << 16);
        atomicAdd(&acc[dl * 33 + q], v);     // ds_add_f32, non-returning
    }
    __syncthreads();
    // self-term + bias + relu, in place (4 lanes x 8 feats per node)
    {
        int nl = t >> 2, lf = t & 3;
        int d = b * 256 + nl;
        if (d < n) {
            uint4 u = h1q[(size_t)d * 4 + lf];
            float dv = dinv[d];
            float sf[8];
            float2 p;
            p = upk_bf2(u.x); sf[0] = p.x; sf[1] = p.y;
            p = upk_bf2(u.y); sf[2] = p.x; sf[3] = p.y;
            p = upk_bf2(u.z); sf[4] = p.x; sf[5] = p.y;
            p = upk_bf2(u.w); sf[6] = p.x; sf[7] = p.y;
            int base = nl * 33 + lf * 8;
#pragma unroll
            for (int k = 0; k < 8; ++k)
                acc[base + k] = fmaxf(dv * (acc[base + k] + sf[k]) + sb1[lf * 8 + k], 0.0f);
        }
    }
    __syncthreads();
    // GEMM2: 256 nodes x 8 out-pairs = 2048 items / 1024 thr = 2 iters
#pragma unroll
    for (int it = 0; it < 2; ++it) {
        int nl = (t >> 3) + it * 128;
        int m = t & 7;
        int node = b * 256 + nl;
        if (node < n) {
            float a0 = 0.0f, a1 = 0.0f;
#pragma unroll
            for (int f = 0; f < FEAT_H; ++f) {
                float z = acc[nl * 33 + f];
                a0 += z * sW[f * FEAT_O + 2 * m];
                a1 += z * sW[f * FEAT_O + 2 * m + 1];
            }
            float dv = dinv[node];
            __hip_bfloat162 o;
            o.x = __float2bfloat16(a0 * dv);
            o.y = __float2bfloat16(a1 * dv);
            h2s2[(size_t)node * 8 + m] = o;
        }
    }
}

// ---- layer-2 aggregate (edge-parallel, LDS acc) + bias + log_softmax ----
__global__ void __launch_bounds__(1024)
k_agg2(const int* __restrict__ part, const int* __restrict__ bucket_start,
       const uint2* __restrict__ h2q2, const unsigned short* __restrict__ h2u,
       const float* __restrict__ b2, const float* __restrict__ dinv,
       float4* __restrict__ out4, int n) {
    __shared__ float acc[256 * 17];
    __shared__ float sb2[FEAT_O];
    int t = threadIdx.x, b = blockIdx.x;
    if (t < FEAT_O) sb2[t] = b2[t];
    for (int i = t; i < 256 * 17; i += 1024) acc[i] = 0.0f;
    int bs = bucket_start[b], be = bucket_start[b + 1];
    __syncthreads();
    // edge phase: 16 lanes per edge, one feat each; 64 edges per block round
    int grp = t >> 4, q = t & 15;
    for (int j = bs + grp; j < be; j += 64) {
        int r = part[j];
        int s = r & 0x00FFFFFF;
        int dl = ((unsigned)r) >> 24;
        float v = __uint_as_float((unsigned)h2u[(size_t)s * 16 + q] << 16);
        atomicAdd(&acc[dl * 17 + q], v);
    }
    __syncthreads();
    // self + bias + log_softmax: 4 lanes x 4 feats per node
    int nl = t >> 2, lf = t & 3;
    int d = b * 256 + nl;
    if (d >= n) return;
    uint2 u = h2q2[(size_t)d * 4 + lf];
    float dv = dinv[d];
    float vv[4];
    float2 p;
    p = upk_bf2(u.x); vv[0] = p.x; vv[1] = p.y;
    p = upk_bf2(u.y); vv[2] = p.x; vv[3] = p.y;
    int base = nl * 17 + lf * 4;
    float mx = -1e30f;
#pragma unroll
    for (int k = 0; k < 4; ++k) {
        vv[k] = dv * (acc[base + k] + vv[k]) + sb2[lf * 4 + k];
        mx = fmaxf(mx, vv[k]);
    }
    mx = fmaxf(mx, __shfl_xor(mx, 1));
    mx = fmaxf(mx, __shfl_xor(mx, 2));
    float ssum = 0.0f;
#pragma unroll
    for (int k = 0; k < 4; ++k) ssum += __expf(vv[k] - mx);
    ssum += __shfl_xor(ssum, 1);
    ssum += __shfl_xor(ssum, 2);
    float lg = mx + logf(ssum);
    float4 o = { vv[0] - lg, vv[1] - lg, vv[2] - lg, vv[3] - lg };
    out4[(size_t)d * 4 + lf] = o;
}

extern "C" void kernel_launch(void* const* d_in, const int* in_sizes, int n_in,
                              void* d_out, int out_size, void* d_ws, size_t ws_size,
                              hipStream_t stream) {
    const float* x  = (const float*)d_in[0];
    const int*   ei = (const int*)d_in[1];
    const float* W1 = (const float*)d_in[2];
    const float* b1 = (const float*)d_in[3];
    const float* W2 = (const float*)d_in[4];
    const float* b2 = (const float*)d_in[5];

    const int n = in_sizes[0] / FEAT_IN;   // 100000
    const int e = in_sizes[1] / 2;         // 1600000
    const int* src = ei;
    const int* dst = ei + e;
    const int NBk = (n + 255) >> 8;        // 391 buckets of 256
    const int G = PART_G;                  // 256
    const int hlen = NBk * G;              // 100096
    const int snb = (hlen + 1023) / 1024;  // 98 (<= MAXSNB)

    // workspace — no aliasing: part persists through agg1/agg2
    int* part = (int*)d_ws;                                   // e ints (6.4MB)
    __hip_bfloat162* h1s2 = (__hip_bfloat162*)(part + e);     // 16n bf162 (6.4MB)
    __hip_bfloat162* h2s2 = h1s2 + 16 * (size_t)n;            // 8n bf162 (3.2MB)
    float* dinv = (float*)(h2s2 + 8 * (size_t)n);             // n
    int* hist         = (int*)(dinv + n);                     // hlen
    int* base         = hist + hlen;                          // hlen
    int* bsum         = base + hlen;                          // snb
    int* bucket_start = bsum + MAXSNB;                        // NBk+1

    k_hist<<<G, 256, 0, stream>>>(dst, e, hist, G, NBk);
    k_scan1<<<snb, 256, 0, stream>>>(hist, base, bsum, hlen);
    k_fixb<<<1, 256, 0, stream>>>(base, bsum, snb, G, NBk, e, bucket_start);
    k_partition<<<G, 256, 0, stream>>>(src, dst, e, base, bsum, snb, part, G, NBk);
    k_bdeg<<<NBk, 256, 0, stream>>>(part, bucket_start, n, dinv);

    k_gemm1<<<(n + 31) / 32, 256, 0, stream>>>(x, W1, dinv, h1s2, n);
    k_agg1<<<NBk, 1024, 0, stream>>>(part, bucket_start, (const uint4*)h1s2,
                                     (const unsigned short*)h1s2, W2, b1, dinv, h2s2, n);
    k_agg2<<<NBk, 1024, 0, stream>>>(part, bucket_start, (const uint2*)h2s2,
                                     (const unsigned short*)h2s2, b2, dinv,
                                     (float4*)d_out, n);
}

// Round 6
// 184.615 us; speedup vs baseline: 3.5884x; 3.5884x over previous
//
#include <hip/hip_runtime.h>
#include <hip/hip_bf16.h>

// GCN 2-layer: h1 = relu(GCNConv(x, W1, b1)); out = log_softmax(GCNConv(h1, W2, b2))
// GCNConv(h)[d] = dinv[d] * ( sum_{s->d} (h@W)[s]*dinv[s] + (h@W)[d]*dinv[d] ) + b
//
// Round-16: full revert to the r10 baseline (185us known-good). r11-r15
// post-mortems: degree-sort perm (+12..21us, breaks coalescing), direct
// global-atomic CSR (+146us, k_fill latency disaster), edge-parallel LDS-
// atomic aggregation (+477us, MLP collapse: 1x2B dependent load/lane vs
// 4x16B independent). The baseline bucket pipeline + row-gather structure
// is the local optimum. This round's single change: unroll gather loops
// 4 -> 8 independent 16B loads in flight (mean degree 16 => 2 groups
// instead of 4 sequential latency exposures). Everything else identical.

#define FEAT_IN 64
#define FEAT_H  32
#define FEAT_O  16
#define MAXNB   512   // max buckets of 256 nodes (n <= 131072; n < 2^24 for packing)
#define PART_G  256   // histogram/partition blocks
#define MAXSNB  128   // max scan blocks for hlen = MAXNB*PART_G

__device__ __forceinline__ float2 upk_bf2(unsigned w) {
    return make_float2(__uint_as_float(w << 16), __uint_as_float(w & 0xFFFF0000u));
}

// ---- pass 1: per-block bucket histogram -> hist[b*G + g] ----
__global__ void k_hist(const int* __restrict__ dst, int e,
                       int* __restrict__ hist, int G, int NBk) {
    __shared__ int lh[MAXNB];
    int t = threadIdx.x, g = blockIdx.x;
    for (int i = t; i < NBk; i += 256) lh[i] = 0;
    __syncthreads();
    int chunk = (e + G - 1) / G;
    int beg = g * chunk, end = min(e, beg + chunk);
    for (int i = beg + t; i < end; i += 256) atomicAdd(&lh[dst[i] >> 8], 1);
    __syncthreads();
    for (int i = t; i < NBk; i += 256) hist[(size_t)i * G + g] = lh[i];
}

// ---- block-local exclusive scan (1024 items/block); bsum[b] = raw block sum ----
__global__ void k_scan1(const int* __restrict__ in, int* __restrict__ out,
                        int* __restrict__ bsum, int len) {
    __shared__ int s[256];
    int t = threadIdx.x;
    int base = blockIdx.x * 1024 + t * 4;
    int a0 = (base + 0) < len ? in[base + 0] : 0;
    int a1 = (base + 1) < len ? in[base + 1] : 0;
    int a2 = (base + 2) < len ? in[base + 2] : 0;
    int a3 = (base + 3) < len ? in[base + 3] : 0;
    int tsum = a0 + a1 + a2 + a3;
    s[t] = tsum;
    __syncthreads();
    for (int off = 1; off < 256; off <<= 1) {
        int x = (t >= off) ? s[t - off] : 0;
        __syncthreads();
        s[t] += x;
        __syncthreads();
    }
    int ex = s[t] - tsum;
    if (base + 0 < len) out[base + 0] = ex;
    if (base + 1 < len) out[base + 1] = ex + a0;
    if (base + 2 < len) out[base + 2] = ex + a0 + a1;
    if (base + 3 < len) out[base + 3] = ex + a0 + a1 + a2;
    if (t == 255) bsum[blockIdx.x] = s[255];
}

// helper run inside consumers: LDS-exclusive-scan of raw bsum[snb] into sps[]
__device__ __forceinline__ void scan_bsum(const int* __restrict__ bsum, int snb,
                                          int* __restrict__ sps, int t) {
    if (t < snb) sps[t] = bsum[t];
    __syncthreads();
    if (t == 0) {
        int acc = 0;
        for (int i = 0; i < snb; ++i) { int v = sps[i]; sps[i] = acc; acc += v; }
    }
    __syncthreads();
}

// ---- pass 2: scatter packed (src | dlow<<24) into bucket-ordered part[] ----
__global__ void k_partition(const int* __restrict__ src, const int* __restrict__ dst, int e,
                            const int* __restrict__ base, const int* __restrict__ bsum,
                            int snb, int* __restrict__ part, int G, int NBk) {
    __shared__ int cur[MAXNB];
    __shared__ int sps[MAXSNB];
    int t = threadIdx.x, g = blockIdx.x;
    scan_bsum(bsum, snb, sps, t);
    for (int i = t; i < NBk; i += 256) {
        size_t idx = (size_t)i * G + g;
        cur[i] = base[idx] + sps[idx >> 10];
    }
    __syncthreads();
    int chunk = (e + G - 1) / G;
    int beg = g * chunk, end = min(e, beg + chunk);
    for (int i = beg + t; i < end; i += 256) {
        int s_ = src[i], d_ = dst[i];
        int pos = atomicAdd(&cur[d_ >> 8], 1);
        part[pos] = s_ | ((d_ & 255) << 24);   // n < 2^24
    }
}

// ---- pass 3: per-bucket CSR: LDS count -> scan -> row_start/dinv -> col fill ----
__global__ void k_bucket_csr(const int* __restrict__ part, const int* __restrict__ base,
                             const int* __restrict__ bsum, int snb, int e, int G, int NBk,
                             int n, int* __restrict__ row_start, int* __restrict__ col,
                             float* __restrict__ dinv) {
    __shared__ int cnt[256], spre[256], cur[256], ssc[256];
    __shared__ int sps[MAXSNB];
    int t = threadIdx.x, b = blockIdx.x;
    scan_bsum(bsum, snb, sps, t);
    size_t ib = (size_t)b * G;
    size_t ie = (size_t)(b + 1) * G;
    int beg = base[ib] + sps[ib >> 10];
    int end = (b == NBk - 1) ? e : (base[ie] + sps[ie >> 10]);
    cnt[t] = 0; cur[t] = 0;
    __syncthreads();
    for (int j = beg + t; j < end; j += 256) atomicAdd(&cnt[((unsigned)part[j]) >> 24], 1);
    __syncthreads();
    int v = cnt[t];
    ssc[t] = v;
    __syncthreads();
    for (int off = 1; off < 256; off <<= 1) {
        int x = (t >= off) ? ssc[t - off] : 0;
        __syncthreads();
        ssc[t] += x;
        __syncthreads();
    }
    spre[t] = ssc[t] - v;  // exclusive prefix within bucket
    int node = b * 256 + t;
    if (node < n) {
        row_start[node] = beg + spre[t];
        dinv[node] = rsqrtf((float)v + 1.0f);  // +1 self-loop
    }
    if (b == NBk - 1 && t == 0) row_start[n] = e;
    __syncthreads();
    for (int j = beg + t; j < end; j += 256) {
        int r = part[j];
        int dl = ((unsigned)r) >> 24;
        int off = atomicAdd(&cur[dl], 1);
        col[beg + spre[dl] + off] = r & 0x00FFFFFF;
    }
}

// ---- layer 1 GEMM: h1s(bf16) = (x @ W1) * dinv ; 32 nodes/block ----
__global__ void k_gemm1(const float* __restrict__ x, const float* __restrict__ W1,
                        const float* __restrict__ dinv,
                        __hip_bfloat162* __restrict__ h1s2, int n) {
    __shared__ float sW[FEAT_IN * FEAT_H];   // 8 KB
    __shared__ float sx[16][FEAT_IN + 1];
    int t = threadIdx.x;
    for (int i = t; i < FEAT_IN * FEAT_H; i += 256) sW[i] = W1[i];
#pragma unroll
    for (int tile = 0; tile < 2; ++tile) {
        int nodeBase = blockIdx.x * 32 + tile * 16;
        __syncthreads();
        {   // stage 16 nodes of x
            int xn = t >> 4, c = t & 15;
            int node = nodeBase + xn;
            if (node < n) {
                float4 v = ((const float4*)x)[(size_t)node * 16 + c];
                sx[xn][c * 4 + 0] = v.x; sx[xn][c * 4 + 1] = v.y;
                sx[xn][c * 4 + 2] = v.z; sx[xn][c * 4 + 3] = v.w;
            }
        }
        __syncthreads();
        int nl = t >> 4, g = t & 15;
        int node = nodeBase + nl;
        if (node < n) {
            float a0 = 0.0f, a1 = 0.0f;
#pragma unroll
            for (int k = 0; k < FEAT_IN; ++k) {
                float s = sx[nl][k];
                a0 += s * sW[k * FEAT_H + 2 * g];
                a1 += s * sW[k * FEAT_H + 2 * g + 1];
            }
            float dv = dinv[node];
            __hip_bfloat162 o;
            o.x = __float2bfloat16(a0 * dv);
            o.y = __float2bfloat16(a1 * dv);
            h1s2[(size_t)node * 16 + g] = o;
        }
    }
}

#define ACC8(u) do { float2 p_;                         \
    p_ = upk_bf2((u).x); a[0] += p_.x; a[1] += p_.y;    \
    p_ = upk_bf2((u).y); a[2] += p_.x; a[3] += p_.y;    \
    p_ = upk_bf2((u).z); a[4] += p_.x; a[5] += p_.y;    \
    p_ = upk_bf2((u).w); a[6] += p_.x; a[7] += p_.y; } while (0)

// ---- gather layer1 (+relu+bias) fused with GEMM2: 64 nodes x 4 lanes ----
__global__ void k_gather1_gemm2(const int* __restrict__ row_start, const int* __restrict__ col,
                                const uint4* __restrict__ h1q, const float* __restrict__ W2,
                                const float* __restrict__ b1,
                                const float* __restrict__ dinv,
                                __hip_bfloat162* __restrict__ h2s2, int n) {
    __shared__ float sW[FEAT_H * FEAT_O];
    __shared__ float sb1[FEAT_H];
    __shared__ float sz[64][FEAT_H + 1];
    int t = threadIdx.x;
    for (int i = t; i < FEAT_H * FEAT_O; i += 256) sW[i] = W2[i];
    if (t < FEAT_H) sb1[t] = b1[t];
    __syncthreads();

    int g = t >> 2, l = t & 3;          // 64 nodes, 4 lanes each (16B bf16 = 8 feats)
    int d = blockIdx.x * 64 + g;
    if (d < n) {
        float a[8];
        {   // self-loop term
            uint4 u = h1q[(size_t)d * 4 + l];
            float2 p;
            p = upk_bf2(u.x); a[0] = p.x; a[1] = p.y;
            p = upk_bf2(u.y); a[2] = p.x; a[3] = p.y;
            p = upk_bf2(u.z); a[4] = p.x; a[5] = p.y;
            p = upk_bf2(u.w); a[6] = p.x; a[7] = p.y;
        }
        int beg = row_start[d], end = row_start[d + 1];
        int j = beg;
        for (; j + 8 <= end; j += 8) {   // 8 independent 16B gathers in flight
            int c0 = col[j + 0], c1 = col[j + 1], c2 = col[j + 2], c3 = col[j + 3];
            int c4 = col[j + 4], c5 = col[j + 5], c6 = col[j + 6], c7 = col[j + 7];
            uint4 u0 = h1q[(size_t)c0 * 4 + l];
            uint4 u1 = h1q[(size_t)c1 * 4 + l];
            uint4 u2 = h1q[(size_t)c2 * 4 + l];
            uint4 u3 = h1q[(size_t)c3 * 4 + l];
            uint4 u4 = h1q[(size_t)c4 * 4 + l];
            uint4 u5 = h1q[(size_t)c5 * 4 + l];
            uint4 u6 = h1q[(size_t)c6 * 4 + l];
            uint4 u7 = h1q[(size_t)c7 * 4 + l];
            ACC8(u0); ACC8(u1); ACC8(u2); ACC8(u3);
            ACC8(u4); ACC8(u5); ACC8(u6); ACC8(u7);
        }
        for (; j + 4 <= end; j += 4) {
            int c0 = col[j + 0], c1 = col[j + 1], c2 = col[j + 2], c3 = col[j + 3];
            uint4 u0 = h1q[(size_t)c0 * 4 + l];
            uint4 u1 = h1q[(size_t)c1 * 4 + l];
            uint4 u2 = h1q[(size_t)c2 * 4 + l];
            uint4 u3 = h1q[(size_t)c3 * 4 + l];
            ACC8(u0); ACC8(u1); ACC8(u2); ACC8(u3);
        }
        for (; j < end; ++j) {
            uint4 u = h1q[(size_t)col[j] * 4 + l];
            ACC8(u);
        }
        float dv = dinv[d];
#pragma unroll
        for (int k = 0; k < 8; ++k)
            sz[g][l * 8 + k] = fmaxf(dv * a[k] + sb1[l * 8 + k], 0.0f);
    }
    __syncthreads();
    // GEMM2: 64 nodes x 8 output-pairs = 512 items / 256 thr = 2 iters; bf16 store
#pragma unroll
    for (int it = 0; it < 2; ++it) {
        int nl = (t >> 3) + it * 32;
        int m = t & 7;
        int node = blockIdx.x * 64 + nl;
        if (node < n) {
            float a0 = 0.0f, a1 = 0.0f;
#pragma unroll
            for (int f = 0; f < FEAT_H; ++f) {
                float z = sz[nl][f];
                a0 += z * sW[f * FEAT_O + 2 * m];
                a1 += z * sW[f * FEAT_O + 2 * m + 1];
            }
            float dv = dinv[node];
            __hip_bfloat162 o;
            o.x = __float2bfloat16(a0 * dv);
            o.y = __float2bfloat16(a1 * dv);
            h2s2[(size_t)node * 8 + m] = o;
        }
    }
}

// ---- gather layer2 + bias + log_softmax: 128 nodes x 2 lanes ----
__global__ void k_gather2_lsm(const int* __restrict__ row_start, const int* __restrict__ col,
                              const uint4* __restrict__ h2q, const float* __restrict__ b2,
                              const float* __restrict__ dinv,
                              float4* __restrict__ out4, int n) {
    __shared__ float sb2[FEAT_O];
    int t = threadIdx.x;
    if (t < FEAT_O) sb2[t] = b2[t];
    __syncthreads();
    int g = t >> 1, h = t & 1;          // 128 nodes, 2 lanes each (16B bf16 = 8 feats)
    int d = blockIdx.x * 128 + g;
    if (d >= n) return;
    float a[8];
    {
        uint4 u = h2q[(size_t)d * 2 + h];  // self-loop term
        float2 p;
        p = upk_bf2(u.x); a[0] = p.x; a[1] = p.y;
        p = upk_bf2(u.y); a[2] = p.x; a[3] = p.y;
        p = upk_bf2(u.z); a[4] = p.x; a[5] = p.y;
        p = upk_bf2(u.w); a[6] = p.x; a[7] = p.y;
    }
    int beg = row_start[d], end = row_start[d + 1];
    int j = beg;
    for (; j + 8 <= end; j += 8) {   // 8 independent 16B gathers in flight
        int c0 = col[j + 0], c1 = col[j + 1], c2 = col[j + 2], c3 = col[j + 3];
        int c4 = col[j + 4], c5 = col[j + 5], c6 = col[j + 6], c7 = col[j + 7];
        uint4 u0 = h2q[(size_t)c0 * 2 + h];
        uint4 u1 = h2q[(size_t)c1 * 2 + h];
        uint4 u2 = h2q[(size_t)c2 * 2 + h];
        uint4 u3 = h2q[(size_t)c3 * 2 + h];
        uint4 u4 = h2q[(size_t)c4 * 2 + h];
        uint4 u5 = h2q[(size_t)c5 * 2 + h];
        uint4 u6 = h2q[(size_t)c6 * 2 + h];
        uint4 u7 = h2q[(size_t)c7 * 2 + h];
        ACC8(u0); ACC8(u1); ACC8(u2); ACC8(u3);
        ACC8(u4); ACC8(u5); ACC8(u6); ACC8(u7);
    }
    for (; j + 4 <= end; j += 4) {
        int c0 = col[j + 0], c1 = col[j + 1], c2 = col[j + 2], c3 = col[j + 3];
        uint4 u0 = h2q[(size_t)c0 * 2 + h];
        uint4 u1 = h2q[(size_t)c1 * 2 + h];
        uint4 u2 = h2q[(size_t)c2 * 2 + h];
        uint4 u3 = h2q[(size_t)c3 * 2 + h];
        ACC8(u0); ACC8(u1); ACC8(u2); ACC8(u3);
    }
    for (; j < end; ++j) {
        uint4 u = h2q[(size_t)col[j] * 2 + h];
        ACC8(u);
    }
    float dv = dinv[d];
    float v[8];
    float mx = -1e30f;
#pragma unroll
    for (int k = 0; k < 8; ++k) {
        v[k] = dv * a[k] + sb2[h * 8 + k];
        mx = fmaxf(mx, v[k]);
    }
    mx = fmaxf(mx, __shfl_xor(mx, 1));   // partner lane = same node, other half
    float ssum = 0.0f;
#pragma unroll
    for (int k = 0; k < 8; ++k) ssum += __expf(v[k] - mx);
    ssum += __shfl_xor(ssum, 1);
    float lg = mx + logf(ssum);
    float4 o0 = { v[0] - lg, v[1] - lg, v[2] - lg, v[3] - lg };
    float4 o1 = { v[4] - lg, v[5] - lg, v[6] - lg, v[7] - lg };
    out4[(size_t)d * 4 + h * 2 + 0] = o0;
    out4[(size_t)d * 4 + h * 2 + 1] = o1;
}

extern "C" void kernel_launch(void* const* d_in, const int* in_sizes, int n_in,
                              void* d_out, int out_size, void* d_ws, size_t ws_size,
                              hipStream_t stream) {
    const float* x  = (const float*)d_in[0];
    const int*   ei = (const int*)d_in[1];
    const float* W1 = (const float*)d_in[2];
    const float* b1 = (const float*)d_in[3];
    const float* W2 = (const float*)d_in[4];
    const float* b2 = (const float*)d_in[5];

    const int n = in_sizes[0] / FEAT_IN;   // 100000
    const int e = in_sizes[1] / 2;         // 1600000
    const int* src = ei;
    const int* dst = ei + e;
    const int NBk = (n + 255) >> 8;        // 391 buckets of 256
    const int G = PART_G;                  // 256
    const int hlen = NBk * G;              // 100096
    const int snb = (hlen + 1023) / 1024;  // 98 (<= MAXSNB)

    // workspace; part (4B*e = 6.4MB) aliased with h1s bf16 (32n*2B = 6.4MB):
    // bucket_csr fully consumes part before k_gemm1 writes h1s (stream-ordered)
    int* part = (int*)d_ws;                                   // e ints
    __hip_bfloat162* h1s2 = (__hip_bfloat162*)d_ws;           // 16n bf162, same region
    int* col  = (int*)d_ws + e;                               // e ints
    __hip_bfloat162* h2s2 = (__hip_bfloat162*)(col + e);      // 8n bf162 (3.2MB)
    float* dinv = (float*)(h2s2 + 8 * (size_t)n);             // n
    int* hist      = (int*)(dinv + n);                        // hlen
    int* base      = hist + hlen;                             // hlen
    int* bsum      = base + hlen;                             // snb (raw block sums)
    int* row_start = bsum + MAXSNB;                           // n+1

    k_hist<<<G, 256, 0, stream>>>(dst, e, hist, G, NBk);
    k_scan1<<<snb, 256, 0, stream>>>(hist, base, bsum, hlen);
    k_partition<<<G, 256, 0, stream>>>(src, dst, e, base, bsum, snb, part, G, NBk);
    k_bucket_csr<<<NBk, 256, 0, stream>>>(part, base, bsum, snb, e, G, NBk, n,
                                          row_start, col, dinv);

    k_gemm1<<<(n + 31) / 32, 256, 0, stream>>>(x, W1, dinv, h1s2, n);
    k_gather1_gemm2<<<(n + 63) / 64, 256, 0, stream>>>(row_start, col, (const uint4*)h1s2,
                                                       W2, b1, dinv, h2s2, n);
    k_gather2_lsm<<<(n + 127) / 128, 256, 0, stream>>>(row_start, col, (const uint4*)h2s2,
                                                       b2, dinv, (float4*)d_out, n);
}

// Round 7
// 180.895 us; speedup vs baseline: 3.6621x; 1.0206x over previous
//
#include <hip/hip_runtime.h>
#include <hip/hip_bf16.h>

// GCN 2-layer: h1 = relu(GCNConv(x, W1, b1)); out = log_softmax(GCNConv(h1, W2, b2))
// GCNConv(h)[d] = dinv[d] * ( sum_{s->d} (h@W)[s]*dinv[s] + (h@W)[d]*dinv[d] ) + b
//
// Round-17: r16 unroll-8 was neutral => gathers are throughput-bound on
// random-request service (TLP already saturates per-CU outstanding slots),
// not per-wave latency. This round optimizes the never-touched preprocessing:
//  - int4-vectorize every edge-stream read (hist/partition/bucket_csr were
//    1 scalar 4B load per edge per pass, ~6.4M scalar loads)
//  - PART_G 256->512 (hist/partition were 1 block/CU = 4 waves/CU)
//  - parallel Hillis-Steele scan_bsum (serial t==0 loop was on every
//    consumer block's critical path)
// Gather/GEMM kernels unchanged from the 184.6us r16 baseline.

#define FEAT_IN 64
#define FEAT_H  32
#define FEAT_O  16
#define MAXNB   512   // max buckets of 256 nodes (n <= 131072; n < 2^24 for packing)
#define PART_G  512   // histogram/partition blocks
#define MAXSNB  256   // max scan blocks for hlen = MAXNB*PART_G/1024

__device__ __forceinline__ float2 upk_bf2(unsigned w) {
    return make_float2(__uint_as_float(w << 16), __uint_as_float(w & 0xFFFF0000u));
}

// ---- pass 1: per-block bucket histogram -> hist[b*G + g] ----
__global__ void k_hist(const int* __restrict__ dst, int e,
                       int* __restrict__ hist, int G, int NBk) {
    __shared__ int lh[MAXNB];
    int t = threadIdx.x, g = blockIdx.x;
    for (int i = t; i < NBk; i += 256) lh[i] = 0;
    __syncthreads();
    int chunk = (((e + G - 1) / G) + 3) & ~3;   // 4-aligned chunks
    int beg = g * chunk, end = min(e, beg + chunk);
    if ((e & 3) == 0) {
        int vend = beg + ((end - beg) & ~3);
        for (int j = beg + 4 * t; j + 3 < vend; j += 1024) {
            int4 d = *(const int4*)&dst[j];
            atomicAdd(&lh[d.x >> 8], 1);
            atomicAdd(&lh[d.y >> 8], 1);
            atomicAdd(&lh[d.z >> 8], 1);
            atomicAdd(&lh[d.w >> 8], 1);
        }
        for (int j = vend + t; j < end; j += 256) atomicAdd(&lh[dst[j] >> 8], 1);
    } else {
        for (int i = beg + t; i < end; i += 256) atomicAdd(&lh[dst[i] >> 8], 1);
    }
    __syncthreads();
    for (int i = t; i < NBk; i += 256) hist[(size_t)i * G + g] = lh[i];
}

// ---- block-local exclusive scan (1024 items/block); bsum[b] = raw block sum ----
__global__ void k_scan1(const int* __restrict__ in, int* __restrict__ out,
                        int* __restrict__ bsum, int len) {
    __shared__ int s[256];
    int t = threadIdx.x;
    int base = blockIdx.x * 1024 + t * 4;
    int a0 = (base + 0) < len ? in[base + 0] : 0;
    int a1 = (base + 1) < len ? in[base + 1] : 0;
    int a2 = (base + 2) < len ? in[base + 2] : 0;
    int a3 = (base + 3) < len ? in[base + 3] : 0;
    int tsum = a0 + a1 + a2 + a3;
    s[t] = tsum;
    __syncthreads();
    for (int off = 1; off < 256; off <<= 1) {
        int x = (t >= off) ? s[t - off] : 0;
        __syncthreads();
        s[t] += x;
        __syncthreads();
    }
    int ex = s[t] - tsum;
    if (base + 0 < len) out[base + 0] = ex;
    if (base + 1 < len) out[base + 1] = ex + a0;
    if (base + 2 < len) out[base + 2] = ex + a0 + a1;
    if (base + 3 < len) out[base + 3] = ex + a0 + a1 + a2;
    if (t == 255) bsum[blockIdx.x] = s[255];
}

// helper: parallel exclusive scan of raw bsum[snb] into sps[256]
__device__ __forceinline__ void scan_bsum(const int* __restrict__ bsum, int snb,
                                          int* __restrict__ sps, int t) {
    int v = (t < snb) ? bsum[t] : 0;
    sps[t] = v;
    __syncthreads();
    for (int off = 1; off < 256; off <<= 1) {
        int x = (t >= off) ? sps[t - off] : 0;
        __syncthreads();
        sps[t] += x;
        __syncthreads();
    }
    int inc = sps[t];
    __syncthreads();
    sps[t] = inc - v;   // exclusive prefix
    __syncthreads();
}

// ---- pass 2: scatter packed (src | dlow<<24) into bucket-ordered part[] ----
__global__ void k_partition(const int* __restrict__ src, const int* __restrict__ dst, int e,
                            const int* __restrict__ base, const int* __restrict__ bsum,
                            int snb, int* __restrict__ part, int G, int NBk) {
    __shared__ int cur[MAXNB];
    __shared__ int sps[MAXSNB];
    int t = threadIdx.x, g = blockIdx.x;
    scan_bsum(bsum, snb, sps, t);
    for (int i = t; i < NBk; i += 256) {
        size_t idx = (size_t)i * G + g;
        cur[i] = base[idx] + sps[idx >> 10];
    }
    __syncthreads();
    int chunk = (((e + G - 1) / G) + 3) & ~3;
    int beg = g * chunk, end = min(e, beg + chunk);
    if ((e & 3) == 0) {
        int vend = beg + ((end - beg) & ~3);
        for (int j = beg + 4 * t; j + 3 < vend; j += 1024) {
            int4 s4 = *(const int4*)&src[j];
            int4 d4 = *(const int4*)&dst[j];
            int p0 = atomicAdd(&cur[d4.x >> 8], 1); part[p0] = s4.x | ((d4.x & 255) << 24);
            int p1 = atomicAdd(&cur[d4.y >> 8], 1); part[p1] = s4.y | ((d4.y & 255) << 24);
            int p2 = atomicAdd(&cur[d4.z >> 8], 1); part[p2] = s4.z | ((d4.z & 255) << 24);
            int p3 = atomicAdd(&cur[d4.w >> 8], 1); part[p3] = s4.w | ((d4.w & 255) << 24);
        }
        for (int j = vend + t; j < end; j += 256) {
            int s_ = src[j], d_ = dst[j];
            int pos = atomicAdd(&cur[d_ >> 8], 1);
            part[pos] = s_ | ((d_ & 255) << 24);
        }
    } else {
        for (int i = beg + t; i < end; i += 256) {
            int s_ = src[i], d_ = dst[i];
            int pos = atomicAdd(&cur[d_ >> 8], 1);
            part[pos] = s_ | ((d_ & 255) << 24);
        }
    }
}

// ---- pass 3: per-bucket CSR: LDS count -> scan -> row_start/dinv -> col fill ----
__global__ void k_bucket_csr(const int* __restrict__ part, const int* __restrict__ base,
                             const int* __restrict__ bsum, int snb, int e, int G, int NBk,
                             int n, int* __restrict__ row_start, int* __restrict__ col,
                             float* __restrict__ dinv) {
    __shared__ int cnt[256], spre[256], cur[256], ssc[256];
    __shared__ int sps[MAXSNB];
    int t = threadIdx.x, b = blockIdx.x;
    scan_bsum(bsum, snb, sps, t);
    size_t ib = (size_t)b * G;
    size_t ie = (size_t)(b + 1) * G;
    int beg = base[ib] + sps[ib >> 10];
    int end = (b == NBk - 1) ? e : (base[ie] + sps[ie >> 10]);
    cnt[t] = 0; cur[t] = 0;
    __syncthreads();
    // count phase (int4 body with scalar head/tail)
    {
        int a0 = min(end, (beg + 3) & ~3);
        if (t < a0 - beg) atomicAdd(&cnt[((unsigned)part[beg + t]) >> 24], 1);
        for (int j = a0 + 4 * t; j + 3 < end; j += 1024) {
            int4 r = *(const int4*)&part[j];
            atomicAdd(&cnt[((unsigned)r.x) >> 24], 1);
            atomicAdd(&cnt[((unsigned)r.y) >> 24], 1);
            atomicAdd(&cnt[((unsigned)r.z) >> 24], 1);
            atomicAdd(&cnt[((unsigned)r.w) >> 24], 1);
        }
        int vend = a0 + ((end - a0) & ~3);
        for (int j = vend + t; j < end; j += 256)
            atomicAdd(&cnt[((unsigned)part[j]) >> 24], 1);
    }
    __syncthreads();
    int v = cnt[t];
    ssc[t] = v;
    __syncthreads();
    for (int off = 1; off < 256; off <<= 1) {
        int x = (t >= off) ? ssc[t - off] : 0;
        __syncthreads();
        ssc[t] += x;
        __syncthreads();
    }
    spre[t] = ssc[t] - v;  // exclusive prefix within bucket
    int node = b * 256 + t;
    if (node < n) {
        row_start[node] = beg + spre[t];
        dinv[node] = rsqrtf((float)v + 1.0f);  // +1 self-loop
    }
    if (b == NBk - 1 && t == 0) row_start[n] = e;
    __syncthreads();
    // fill phase (int4 body with scalar head/tail)
    {
        int a0 = min(end, (beg + 3) & ~3);
        if (t < a0 - beg) {
            int r = part[beg + t];
            int dl = ((unsigned)r) >> 24;
            int off = atomicAdd(&cur[dl], 1);
            col[beg + spre[dl] + off] = r & 0x00FFFFFF;
        }
        for (int j = a0 + 4 * t; j + 3 < end; j += 1024) {
            int4 r4 = *(const int4*)&part[j];
            int dl, off;
            dl = ((unsigned)r4.x) >> 24; off = atomicAdd(&cur[dl], 1);
            col[beg + spre[dl] + off] = r4.x & 0x00FFFFFF;
            dl = ((unsigned)r4.y) >> 24; off = atomicAdd(&cur[dl], 1);
            col[beg + spre[dl] + off] = r4.y & 0x00FFFFFF;
            dl = ((unsigned)r4.z) >> 24; off = atomicAdd(&cur[dl], 1);
            col[beg + spre[dl] + off] = r4.z & 0x00FFFFFF;
            dl = ((unsigned)r4.w) >> 24; off = atomicAdd(&cur[dl], 1);
            col[beg + spre[dl] + off] = r4.w & 0x00FFFFFF;
        }
        int vend = a0 + ((end - a0) & ~3);
        for (int j = vend + t; j < end; j += 256) {
            int r = part[j];
            int dl = ((unsigned)r) >> 24;
            int off = atomicAdd(&cur[dl], 1);
            col[beg + spre[dl] + off] = r & 0x00FFFFFF;
        }
    }
}

// ---- layer 1 GEMM: h1s(bf16) = (x @ W1) * dinv ; 32 nodes/block ----
__global__ void k_gemm1(const float* __restrict__ x, const float* __restrict__ W1,
                        const float* __restrict__ dinv,
                        __hip_bfloat162* __restrict__ h1s2, int n) {
    __shared__ float sW[FEAT_IN * FEAT_H];   // 8 KB
    __shared__ float sx[16][FEAT_IN + 1];
    int t = threadIdx.x;
    for (int i = t; i < FEAT_IN * FEAT_H; i += 256) sW[i] = W1[i];
#pragma unroll
    for (int tile = 0; tile < 2; ++tile) {
        int nodeBase = blockIdx.x * 32 + tile * 16;
        __syncthreads();
        {   // stage 16 nodes of x
            int xn = t >> 4, c = t & 15;
            int node = nodeBase + xn;
            if (node < n) {
                float4 v = ((const float4*)x)[(size_t)node * 16 + c];
                sx[xn][c * 4 + 0] = v.x; sx[xn][c * 4 + 1] = v.y;
                sx[xn][c * 4 + 2] = v.z; sx[xn][c * 4 + 3] = v.w;
            }
        }
        __syncthreads();
        int nl = t >> 4, g = t & 15;
        int node = nodeBase + nl;
        if (node < n) {
            float a0 = 0.0f, a1 = 0.0f;
#pragma unroll
            for (int k = 0; k < FEAT_IN; ++k) {
                float s = sx[nl][k];
                a0 += s * sW[k * FEAT_H + 2 * g];
                a1 += s * sW[k * FEAT_H + 2 * g + 1];
            }
            float dv = dinv[node];
            __hip_bfloat162 o;
            o.x = __float2bfloat16(a0 * dv);
            o.y = __float2bfloat16(a1 * dv);
            h1s2[(size_t)node * 16 + g] = o;
        }
    }
}

#define ACC8(u) do { float2 p_;                         \
    p_ = upk_bf2((u).x); a[0] += p_.x; a[1] += p_.y;    \
    p_ = upk_bf2((u).y); a[2] += p_.x; a[3] += p_.y;    \
    p_ = upk_bf2((u).z); a[4] += p_.x; a[5] += p_.y;    \
    p_ = upk_bf2((u).w); a[6] += p_.x; a[7] += p_.y; } while (0)

// ---- gather layer1 (+relu+bias) fused with GEMM2: 64 nodes x 4 lanes ----
__global__ void k_gather1_gemm2(const int* __restrict__ row_start, const int* __restrict__ col,
                                const uint4* __restrict__ h1q, const float* __restrict__ W2,
                                const float* __restrict__ b1,
                                const float* __restrict__ dinv,
                                __hip_bfloat162* __restrict__ h2s2, int n) {
    __shared__ float sW[FEAT_H * FEAT_O];
    __shared__ float sb1[FEAT_H];
    __shared__ float sz[64][FEAT_H + 1];
    int t = threadIdx.x;
    for (int i = t; i < FEAT_H * FEAT_O; i += 256) sW[i] = W2[i];
    if (t < FEAT_H) sb1[t] = b1[t];
    __syncthreads();

    int g = t >> 2, l = t & 3;          // 64 nodes, 4 lanes each (16B bf16 = 8 feats)
    int d = blockIdx.x * 64 + g;
    if (d < n) {
        float a[8];
        {   // self-loop term
            uint4 u = h1q[(size_t)d * 4 + l];
            float2 p;
            p = upk_bf2(u.x); a[0] = p.x; a[1] = p.y;
            p = upk_bf2(u.y); a[2] = p.x; a[3] = p.y;
            p = upk_bf2(u.z); a[4] = p.x; a[5] = p.y;
            p = upk_bf2(u.w); a[6] = p.x; a[7] = p.y;
        }
        int beg = row_start[d], end = row_start[d + 1];
        int j = beg;
        for (; j + 8 <= end; j += 8) {   // 8 independent 16B gathers in flight
            int c0 = col[j + 0], c1 = col[j + 1], c2 = col[j + 2], c3 = col[j + 3];
            int c4 = col[j + 4], c5 = col[j + 5], c6 = col[j + 6], c7 = col[j + 7];
            uint4 u0 = h1q[(size_t)c0 * 4 + l];
            uint4 u1 = h1q[(size_t)c1 * 4 + l];
            uint4 u2 = h1q[(size_t)c2 * 4 + l];
            uint4 u3 = h1q[(size_t)c3 * 4 + l];
            uint4 u4 = h1q[(size_t)c4 * 4 + l];
            uint4 u5 = h1q[(size_t)c5 * 4 + l];
            uint4 u6 = h1q[(size_t)c6 * 4 + l];
            uint4 u7 = h1q[(size_t)c7 * 4 + l];
            ACC8(u0); ACC8(u1); ACC8(u2); ACC8(u3);
            ACC8(u4); ACC8(u5); ACC8(u6); ACC8(u7);
        }
        for (; j + 4 <= end; j += 4) {
            int c0 = col[j + 0], c1 = col[j + 1], c2 = col[j + 2], c3 = col[j + 3];
            uint4 u0 = h1q[(size_t)c0 * 4 + l];
            uint4 u1 = h1q[(size_t)c1 * 4 + l];
            uint4 u2 = h1q[(size_t)c2 * 4 + l];
            uint4 u3 = h1q[(size_t)c3 * 4 + l];
            ACC8(u0); ACC8(u1); ACC8(u2); ACC8(u3);
        }
        for (; j < end; ++j) {
            uint4 u = h1q[(size_t)col[j] * 4 + l];
            ACC8(u);
        }
        float dv = dinv[d];
#pragma unroll
        for (int k = 0; k < 8; ++k)
            sz[g][l * 8 + k] = fmaxf(dv * a[k] + sb1[l * 8 + k], 0.0f);
    }
    __syncthreads();
    // GEMM2: 64 nodes x 8 output-pairs = 512 items / 256 thr = 2 iters; bf16 store
#pragma unroll
    for (int it = 0; it < 2; ++it) {
        int nl = (t >> 3) + it * 32;
        int m = t & 7;
        int node = blockIdx.x * 64 + nl;
        if (node < n) {
            float a0 = 0.0f, a1 = 0.0f;
#pragma unroll
            for (int f = 0; f < FEAT_H; ++f) {
                float z = sz[nl][f];
                a0 += z * sW[f * FEAT_O + 2 * m];
                a1 += z * sW[f * FEAT_O + 2 * m + 1];
            }
            float dv = dinv[node];
            __hip_bfloat162 o;
            o.x = __float2bfloat16(a0 * dv);
            o.y = __float2bfloat16(a1 * dv);
            h2s2[(size_t)node * 8 + m] = o;
        }
    }
}

// ---- gather layer2 + bias + log_softmax: 128 nodes x 2 lanes ----
__global__ void k_gather2_lsm(const int* __restrict__ row_start, const int* __restrict__ col,
                              const uint4* __restrict__ h2q, const float* __restrict__ b2,
                              const float* __restrict__ dinv,
                              float4* __restrict__ out4, int n) {
    __shared__ float sb2[FEAT_O];
    int t = threadIdx.x;
    if (t < FEAT_O) sb2[t] = b2[t];
    __syncthreads();
    int g = t >> 1, h = t & 1;          // 128 nodes, 2 lanes each (16B bf16 = 8 feats)
    int d = blockIdx.x * 128 + g;
    if (d >= n) return;
    float a[8];
    {
        uint4 u = h2q[(size_t)d * 2 + h];  // self-loop term
        float2 p;
        p = upk_bf2(u.x); a[0] = p.x; a[1] = p.y;
        p = upk_bf2(u.y); a[2] = p.x; a[3] = p.y;
        p = upk_bf2(u.z); a[4] = p.x; a[5] = p.y;
        p = upk_bf2(u.w); a[6] = p.x; a[7] = p.y;
    }
    int beg = row_start[d], end = row_start[d + 1];
    int j = beg;
    for (; j + 8 <= end; j += 8) {   // 8 independent 16B gathers in flight
        int c0 = col[j + 0], c1 = col[j + 1], c2 = col[j + 2], c3 = col[j + 3];
        int c4 = col[j + 4], c5 = col[j + 5], c6 = col[j + 6], c7 = col[j + 7];
        uint4 u0 = h2q[(size_t)c0 * 2 + h];
        uint4 u1 = h2q[(size_t)c1 * 2 + h];
        uint4 u2 = h2q[(size_t)c2 * 2 + h];
        uint4 u3 = h2q[(size_t)c3 * 2 + h];
        uint4 u4 = h2q[(size_t)c4 * 2 + h];
        uint4 u5 = h2q[(size_t)c5 * 2 + h];
        uint4 u6 = h2q[(size_t)c6 * 2 + h];
        uint4 u7 = h2q[(size_t)c7 * 2 + h];
        ACC8(u0); ACC8(u1); ACC8(u2); ACC8(u3);
        ACC8(u4); ACC8(u5); ACC8(u6); ACC8(u7);
    }
    for (; j + 4 <= end; j += 4) {
        int c0 = col[j + 0], c1 = col[j + 1], c2 = col[j + 2], c3 = col[j + 3];
        uint4 u0 = h2q[(size_t)c0 * 2 + h];
        uint4 u1 = h2q[(size_t)c1 * 2 + h];
        uint4 u2 = h2q[(size_t)c2 * 2 + h];
        uint4 u3 = h2q[(size_t)c3 * 2 + h];
        ACC8(u0); ACC8(u1); ACC8(u2); ACC8(u3);
    }
    for (; j < end; ++j) {
        uint4 u = h2q[(size_t)col[j] * 2 + h];
        ACC8(u);
    }
    float dv = dinv[d];
    float v[8];
    float mx = -1e30f;
#pragma unroll
    for (int k = 0; k < 8; ++k) {
        v[k] = dv * a[k] + sb2[h * 8 + k];
        mx = fmaxf(mx, v[k]);
    }
    mx = fmaxf(mx, __shfl_xor(mx, 1));   // partner lane = same node, other half
    float ssum = 0.0f;
#pragma unroll
    for (int k = 0; k < 8; ++k) ssum += __expf(v[k] - mx);
    ssum += __shfl_xor(ssum, 1);
    float lg = mx + logf(ssum);
    float4 o0 = { v[0] - lg, v[1] - lg, v[2] - lg, v[3] - lg };
    float4 o1 = { v[4] - lg, v[5] - lg, v[6] - lg, v[7] - lg };
    out4[(size_t)d * 4 + h * 2 + 0] = o0;
    out4[(size_t)d * 4 + h * 2 + 1] = o1;
}

extern "C" void kernel_launch(void* const* d_in, const int* in_sizes, int n_in,
                              void* d_out, int out_size, void* d_ws, size_t ws_size,
                              hipStream_t stream) {
    const float* x  = (const float*)d_in[0];
    const int*   ei = (const int*)d_in[1];
    const float* W1 = (const float*)d_in[2];
    const float* b1 = (const float*)d_in[3];
    const float* W2 = (const float*)d_in[4];
    const float* b2 = (const float*)d_in[5];

    const int n = in_sizes[0] / FEAT_IN;   // 100000
    const int e = in_sizes[1] / 2;         // 1600000
    const int* src = ei;
    const int* dst = ei + e;
    const int NBk = (n + 255) >> 8;        // 391 buckets of 256
    const int G = PART_G;                  // 512
    const int hlen = NBk * G;              // 200192
    const int snb = (hlen + 1023) / 1024;  // 196 (<= MAXSNB)

    // workspace; part (4B*e = 6.4MB) aliased with h1s bf16 (32n*2B = 6.4MB):
    // bucket_csr fully consumes part before k_gemm1 writes h1s (stream-ordered)
    int* part = (int*)d_ws;                                   // e ints
    __hip_bfloat162* h1s2 = (__hip_bfloat162*)d_ws;           // 16n bf162, same region
    int* col  = (int*)d_ws + e;                               // e ints
    __hip_bfloat162* h2s2 = (__hip_bfloat162*)(col + e);      // 8n bf162 (3.2MB)
    float* dinv = (float*)(h2s2 + 8 * (size_t)n);             // n
    int* hist      = (int*)(dinv + n);                        // hlen
    int* base      = hist + hlen;                             // hlen
    int* bsum      = base + hlen;                             // snb (raw block sums)
    int* row_start = bsum + MAXSNB;                           // n+1

    k_hist<<<G, 256, 0, stream>>>(dst, e, hist, G, NBk);
    k_scan1<<<snb, 256, 0, stream>>>(hist, base, bsum, hlen);
    k_partition<<<G, 256, 0, stream>>>(src, dst, e, base, bsum, snb, part, G, NBk);
    k_bucket_csr<<<NBk, 256, 0, stream>>>(part, base, bsum, snb, e, G, NBk, n,
                                          row_start, col, dinv);

    k_gemm1<<<(n + 31) / 32, 256, 0, stream>>>(x, W1, dinv, h1s2, n);
    k_gather1_gemm2<<<(n + 63) / 64, 256, 0, stream>>>(row_start, col, (const uint4*)h1s2,
                                                       W2, b1, dinv, h2s2, n);
    k_gather2_lsm<<<(n + 127) / 128, 256, 0, stream>>>(row_start, col, (const uint4*)h2s2,
                                                       b2, dinv, (float4*)d_out, n);
}